// Round 9
// baseline (216.733 us; speedup 1.0000x reference)
//
#include <hip/hip_runtime.h>
#include <math.h>

#define BATCH 32
#define CH 256
#define HW 4096
#define KSEL 8
#define EPSV 1e-5f

typedef __attribute__((ext_vector_type(8))) short short8;
typedef __attribute__((ext_vector_type(4))) float f32x4;

// ---- K1: raw-x Gram partials (256x256 per (b,q)) + fused s/sq partials ----
// 512 threads = 8 waves (2x4), wave tile 128x64, bf16 16x16x32 MFMA,
// C1 = H*(H + 2L)^T (trunc split; drops L*L^T and lo-rounding terms ~1e-7 rel).
// Staging: row=(t>>4)+32i, col16=t&15 -> wave load = 4 x 256B contiguous.
// LDS: DOUBLE-BUFFERED XOR-granule layout, 128KB total; one barrier per chunk:
//   MFMA(kb, buf[kb&1]) ; convert(kb+1) -> buf[(kb+1)&1] ; load(kb+2) ; barrier
// Single f[8] register buffer (round-7 footprint — no spills).
__global__ __launch_bounds__(512, 1) void gram256(const float* __restrict__ x,
                                                  float* __restrict__ cosP,
                                                  float* __restrict__ sP,
                                                  float* __restrict__ sqP) {
    int z = blockIdx.x;             // 0..255
    int b = z >> 3, q = z & 7;      // Q=8, klen=512
    const float* xb = x + (size_t)b * CH * HW;

    __shared__ unsigned short Hh[2][CH * 64];
    __shared__ unsigned short Hl[2][CH * 64];

    int t = threadIdx.x, lane = t & 63, w = t >> 6;
    int wr = (w >> 2) * 128, wc = (w & 3) * 64;
    int fr = lane & 15, fg = lane >> 4;

    // staging geometry (coalesced: 4 x 256B contiguous per wave-load)
    int rowbase = t >> 4;            // 0..31 ; row_i = rowbase + 32*i
    int col16 = t & 15;              // 16B chunk within the 256B row-chunk
    int gr = col16 >> 1;             // granule 0..7
    int halfo = (col16 & 1) * 4;     // short offset within granule
    const float4* srcb4 = (const float4*)xb + (size_t)rowbase * (HW / 4) + q * 128 + col16;

    float sl[8] = {}, sql[8] = {};
    f32x4 acc[8][4] = {};
    float4 f[8];

#define LOAD8(KB) { const float4* sp = srcb4 + (size_t)(KB) * 16;                  \
    _Pragma("unroll") for (int i = 0; i < 8; ++i) f[i] = sp[(size_t)i * 32768]; }

#define CONVERT8(BUF) { _Pragma("unroll") for (int i = 0; i < 8; ++i) {            \
    float4 v = f[i];                                                               \
    sl[i] += v.x + v.y + v.z + v.w;                                                \
    sql[i] += v.x * v.x + v.y * v.y + v.z * v.z + v.w * v.w;                       \
    unsigned u0 = __float_as_uint(v.x), u1 = __float_as_uint(v.y);                 \
    unsigned u2 = __float_as_uint(v.z), u3 = __float_as_uint(v.w);                 \
    unsigned hp0 = (u0 >> 16) | (u1 & 0xffff0000u);                                \
    unsigned hp1 = (u2 >> 16) | (u3 & 0xffff0000u);                                \
    float lo0 = v.x - __uint_as_float(u0 & 0xffff0000u);                           \
    float lo1 = v.y - __uint_as_float(u1 & 0xffff0000u);                           \
    float lo2 = v.z - __uint_as_float(u2 & 0xffff0000u);                           \
    float lo3 = v.w - __uint_as_float(u3 & 0xffff0000u);                           \
    lo0 += lo0; lo1 += lo1; lo2 += lo2; lo3 += lo3;                                \
    unsigned lp0 = (__float_as_uint(lo0) >> 16) | (__float_as_uint(lo1) & 0xffff0000u); \
    unsigned lp1 = (__float_as_uint(lo2) >> 16) | (__float_as_uint(lo3) & 0xffff0000u); \
    int r = rowbase + 32 * i;                                                      \
    int adr = r * 64 + ((gr ^ (r & 7)) * 8) + halfo;                               \
    *(uint2*)&Hh[BUF][adr] = make_uint2(hp0, hp1);                                 \
    *(uint2*)&Hl[BUF][adr] = make_uint2(lp0, lp1);                                 \
} }

#define MFMA_PHASE(BUF) { _Pragma("unroll") for (int ks = 0; ks < 2; ++ks) {       \
    int gk = ks * 4 + fg;                                                          \
    short8 af[8], bh[4], bl[4];                                                    \
    _Pragma("unroll") for (int mi = 0; mi < 8; ++mi) {                             \
        int r = wr + mi * 16 + fr;                                                 \
        af[mi] = *(const short8*)&Hh[BUF][r * 64 + ((gk ^ (r & 7)) * 8)];          \
    }                                                                              \
    _Pragma("unroll") for (int nj = 0; nj < 4; ++nj) {                             \
        int r = wc + nj * 16 + fr;                                                 \
        int rb = r * 64 + ((gk ^ (r & 7)) * 8);                                    \
        bh[nj] = *(const short8*)&Hh[BUF][rb];                                     \
        bl[nj] = *(const short8*)&Hl[BUF][rb];                                     \
    }                                                                              \
    _Pragma("unroll") for (int mi = 0; mi < 8; ++mi)                               \
        _Pragma("unroll") for (int nj = 0; nj < 4; ++nj) {                         \
            acc[mi][nj] = __builtin_amdgcn_mfma_f32_16x16x32_bf16(af[mi], bh[nj], acc[mi][nj], 0, 0, 0); \
            acc[mi][nj] = __builtin_amdgcn_mfma_f32_16x16x32_bf16(af[mi], bl[nj], acc[mi][nj], 0, 0, 0); \
        }                                                                          \
} }

    // prologue: chunk 0 -> buf0, issue loads for chunk 1
    LOAD8(0)
    CONVERT8(0)
    LOAD8(1)
    __syncthreads();

#pragma unroll
    for (int kb = 0; kb < 8; ++kb) {
        MFMA_PHASE(kb & 1)                   // loads for kb+1 land under this
        if (kb < 7) {
            CONVERT8((kb + 1) & 1)           // fill the other buffer
            if (kb < 6) LOAD8(kb + 2)        // issue next loads (covered by barrier+MFMA)
        }
        __syncthreads();                     // buf[(kb+1)&1] ready; buf[kb&1] free
    }

    // stats: reduce across the 16 col-chunk threads of each row
#pragma unroll
    for (int i = 0; i < 8; ++i) {
#pragma unroll
        for (int off = 1; off < 16; off <<= 1) {
            sl[i] += __shfl_xor(sl[i], off);
            sql[i] += __shfl_xor(sql[i], off);
        }
    }
    if ((t & 15) == 0) {
#pragma unroll
        for (int i = 0; i < 8; ++i) {
            int r = rowbase + 32 * i;
            sP[(size_t)z * CH + r] = sl[i];
            sqP[(size_t)z * CH + r] = sql[i];
        }
    }

    float* Cp = cosP + (size_t)z * CH * CH;
#pragma unroll
    for (int mi = 0; mi < 8; ++mi)
#pragma unroll
        for (int nj = 0; nj < 4; ++nj) {
#pragma unroll
            for (int reg = 0; reg < 4; ++reg) {
                int r = wr + mi * 16 + fg * 4 + reg;
                int c = wc + nj * 16 + fr;
                Cp[(size_t)r * CH + c] = acc[mi][nj][reg];
            }
        }
#undef LOAD8
#undef CONVERT8
#undef MFMA_PHASE
}

// ---- K2: finalize per-(b,c) stats from the 8 q-partials ----
__global__ __launch_bounds__(256) void finalize_kernel(const float* __restrict__ sP,
                                                       const float* __restrict__ sqP,
                                                       float* __restrict__ s,
                                                       float* __restrict__ sq,
                                                       float* __restrict__ invn) {
    int b = blockIdx.x, c = threadIdx.x;
    float S = 0.f, Q = 0.f;
#pragma unroll
    for (int q = 0; q < 8; ++q) {
        S += sP[(size_t)(b * 8 + q) * CH + c];
        Q += sqP[(size_t)(b * 8 + q) * CH + c];
    }
    s[b * CH + c] = S;
    sq[b * CH + c] = Q;
    invn[b * CH + c] = 1.0f / fmaxf(sqrtf(Q), 1e-12f);
}

// ---- K3: weighted sum of partials -> R[256][256] (invn applied per batch) ----
__global__ __launch_bounds__(1024) void reduceP(const float* __restrict__ cosP,
                                                const float* __restrict__ invn,
                                                float* __restrict__ R) {
    int r = blockIdx.x;
    int t = threadIdx.x;
    int d = t & 255, pg = t >> 8;          // 4 groups of 8 batches
    const float* base = cosP + (size_t)r * CH + d;
    float acc = 0.f;
    for (int b = pg * 8; b < pg * 8 + 8; ++b) {
        float part = 0.f;
#pragma unroll
        for (int q = 0; q < 8; ++q)
            part += base[(size_t)(b * 8 + q) * (CH * CH)];
        acc += part * invn[b * CH + d] * invn[b * CH + r];
    }
    __shared__ float red[1024];
    red[t] = acc;
    __syncthreads();
    if (t < 256)
        R[(size_t)r * CH + t] = red[t] + red[t + 256] + red[t + 512] + red[t + 768];
}

// -------- K4: symmetrize (R + R^T) + top-8 smallest |cos| per column --------
__global__ __launch_bounds__(256) void symtopk(const float* __restrict__ R,
                                               int* __restrict__ idx) {
    int c = blockIdx.x;
    int d = threadIdx.x;
    float v = fabsf((R[(size_t)c * CH + d] + R[(size_t)d * CH + c]) * (0.5f / BATCH));

    __shared__ unsigned long long keys[CH];
    __shared__ unsigned long long wmin[4];
    __shared__ unsigned long long bmin;

    keys[d] = ((unsigned long long)__float_as_uint(v) << 32) | (unsigned)d;
    __syncthreads();

    for (int i = 0; i < KSEL; ++i) {
        unsigned long long k = keys[d];
        for (int off = 32; off; off >>= 1) {
            unsigned long long o = __shfl_down(k, off);
            k = (o < k) ? o : k;
        }
        if ((d & 63) == 0) wmin[d >> 6] = k;
        __syncthreads();
        if (d == 0) {
            unsigned long long m = wmin[0];
            if (wmin[1] < m) m = wmin[1];
            if (wmin[2] < m) m = wmin[2];
            if (wmin[3] < m) m = wmin[3];
            bmin = m;
            idx[c * KSEL + i] = (int)(m & 0xffffffffu);
        }
        __syncthreads();
        int sel = (int)(bmin & 0xffffffffu);
        if (d == sel) keys[d] = 0xffffffffffffffffULL;
        __syncthreads();
    }
}

// ---------------- K5: gathered group statistics ----------------
__global__ __launch_bounds__(256) void groupstat_kernel(const float* __restrict__ s,
                                                        const float* __restrict__ sq,
                                                        const int* __restrict__ idx,
                                                        float* __restrict__ mean,
                                                        float* __restrict__ inv) {
    int b = blockIdx.x, c = threadIdx.x;
    float gs = s[b * CH + c], gq = sq[b * CH + c];
#pragma unroll
    for (int i = 1; i < KSEL; ++i) {
        int d = idx[c * KSEL + i];
        gs += s[b * CH + d];
        gq += sq[b * CH + d];
    }
    const float Ninv = 1.0f / (float)(KSEL * HW);
    float m = gs * Ninv;
    float var = gq * Ninv - m * m;
    mean[b * CH + c] = m;
    inv[b * CH + c]  = rsqrtf(var + EPSV);
}

// ---------------- K6: normalize ----------------
__global__ __launch_bounds__(256) void norm_kernel(const float* __restrict__ x,
                                                   const float* __restrict__ mean,
                                                   const float* __restrict__ inv,
                                                   const float* __restrict__ gamma,
                                                   const float* __restrict__ beta,
                                                   float* __restrict__ out) {
    int i = blockIdx.x * 256 + threadIdx.x;
    int bc = i >> 10;
    int c  = bc & (CH - 1);
    float m = mean[bc], v = inv[bc];
    float g  = gamma[c] * v;
    float bt = beta[c] - m * g;
    float4 xv = ((const float4*)x)[i];
    float4 o;
    o.x = xv.x * g + bt;
    o.y = xv.y * g + bt;
    o.z = xv.z * g + bt;
    o.w = xv.w * g + bt;
    ((float4*)out)[i] = o;
}

extern "C" void kernel_launch(void* const* d_in, const int* in_sizes, int n_in,
                              void* d_out, int out_size, void* d_ws, size_t ws_size,
                              hipStream_t stream) {
    const float* x     = (const float*)d_in[0];
    const float* gamma = (const float*)d_in[1];
    const float* beta  = (const float*)d_in[2];
    float* out = (float*)d_out;

    // Gram partials (256 x 256KB = 64 MB) live in d_out (128 MiB); norm_kernel
    // overwrites every byte of d_out at the end.
    float* cosP = (float*)d_out;

    // ws: small arrays only
    float* ws   = (float*)d_ws;
    float* sP   = ws;                         // 256*256 partial s
    float* sqP  = sP + 256 * CH;              // 256*256 partial sq
    float* s    = sqP + 256 * CH;
    float* sq   = s + BATCH * CH;
    float* invn = sq + BATCH * CH;
    float* mean = invn + BATCH * CH;
    float* inv  = mean + BATCH * CH;
    float* R    = inv + BATCH * CH;           // 256*256
    int*   idx  = (int*)(R + CH * CH);        // 256*8

    gram256<<<256, 512, 0, stream>>>(x, cosP, sP, sqP);
    finalize_kernel<<<BATCH, 256, 0, stream>>>(sP, sqP, s, sq, invn);
    reduceP<<<CH, 1024, 0, stream>>>(cosP, invn, R);
    symtopk<<<CH, 256, 0, stream>>>(R, idx);
    groupstat_kernel<<<BATCH, 256, 0, stream>>>(s, sq, idx, mean, inv);
    norm_kernel<<<(BATCH * CH * HW / 4) / 256, 256, 0, stream>>>(x, mean, inv, gamma, beta, out);
}

// Round 10
// 108.516 us; speedup vs baseline: 1.9972x; 1.9972x over previous
//
#include <hip/hip_runtime.h>
#include <math.h>

#define BATCH 32
#define CH 256
#define HW 4096
#define KSEL 8
#define EPSV 1e-5f

typedef __attribute__((ext_vector_type(8))) short short8;
typedef __attribute__((ext_vector_type(4))) float f32x4;

__device__ __forceinline__ void gload16(const void* g, void* l) {
    __builtin_amdgcn_global_load_lds((const __attribute__((address_space(1))) void*)g,
                                     (__attribute__((address_space(3))) void*)l, 16, 0, 0);
}

// ---- K1: raw-x Gram partials (256x256 per (b,q)) + fused s/sq partials ----
// 512 threads = 8 waves (2x4), wave tile 128x64, bf16 16x16x32 MFMA,
// C1 = H*(H+2L)^T trunc split. KC=32, 16 chunks per block.
// Front-end: global_load_lds DMA of raw fp32 into ldsF[2] (per-wave-private
// quarters), counted vmcnt(4) + RAW s_barrier (no vmcnt(0) drain!), then
// LDS->reg convert -> Hh/Hl (granule-XOR layout), then MFMA.
__global__ __launch_bounds__(512, 1) void gram256(const float* __restrict__ x,
                                                  float* __restrict__ cosP,
                                                  float* __restrict__ sP,
                                                  float* __restrict__ sqP) {
    int z = blockIdx.x;             // 0..255
    int b = z >> 3, q = z & 7;      // klen = 512
    const float* xb = x + (size_t)b * CH * HW;

    __shared__ float4 ldsF[2][2048];            // 2 x 32 KB fp32 staging
    __shared__ unsigned short Hh[CH * 32];      // 16 KB
    __shared__ unsigned short Hl[CH * 32];      // 16 KB

    int t = threadIdx.x, lane = t & 63, w = t >> 6;
    int wr = (w >> 2) * 128, wc = (w & 3) * 64;
    int fr = lane & 15, fg = lane >> 4;
    int rl = lane >> 3;              // 0..7 row-in-issue
    int gs = lane & 7;               // dest granule slot (16B units)
    int kbase = q * 512;

    float sl[4] = {}, sql[4] = {};
    f32x4 acc[8][4] = {};

    // DMA one chunk (4 issues of 1KB per wave); global granule pre-swizzled.
#define ISSUE(KB, BUF) {                                                          \
    int k0 = kbase + (KB) * 32;                                                   \
    _Pragma("unroll") for (int j = 0; j < 4; ++j) {                               \
        int row = w * 32 + j * 8 + rl;                                            \
        const float* src = xb + (size_t)row * HW + k0 + ((gs ^ rl) * 4);          \
        gload16(src, &ldsF[BUF][(w * 4 + j) * 64]);                               \
    } }

    // Convert own quarter of ldsF[BUF] -> Hh/Hl + s/sq accumulation.
#define CONVERT(BUF) {                                                            \
    _Pragma("unroll") for (int j = 0; j < 4; ++j) {                               \
        float4 v = ldsF[BUF][(w * 4 + j) * 64 + lane];                            \
        int row = w * 32 + j * 8 + rl;                                            \
        int G = gs ^ rl;                                                          \
        sl[j] += v.x + v.y + v.z + v.w;                                           \
        sql[j] += v.x * v.x + v.y * v.y + v.z * v.z + v.w * v.w;                  \
        unsigned u0 = __float_as_uint(v.x), u1 = __float_as_uint(v.y);            \
        unsigned u2 = __float_as_uint(v.z), u3 = __float_as_uint(v.w);            \
        unsigned hp0 = (u0 >> 16) | (u1 & 0xffff0000u);                           \
        unsigned hp1 = (u2 >> 16) | (u3 & 0xffff0000u);                           \
        float lo0 = v.x - __uint_as_float(u0 & 0xffff0000u);                      \
        float lo1 = v.y - __uint_as_float(u1 & 0xffff0000u);                      \
        float lo2 = v.z - __uint_as_float(u2 & 0xffff0000u);                      \
        float lo3 = v.w - __uint_as_float(u3 & 0xffff0000u);                      \
        lo0 += lo0; lo1 += lo1; lo2 += lo2; lo3 += lo3;                           \
        unsigned lp0 = (__float_as_uint(lo0) >> 16) | (__float_as_uint(lo1) & 0xffff0000u); \
        unsigned lp1 = (__float_as_uint(lo2) >> 16) | (__float_as_uint(lo3) & 0xffff0000u); \
        int adr = row * 32 + (((G >> 1) ^ (row & 3)) * 8) + (G & 1) * 4;          \
        *(uint2*)&Hh[adr] = make_uint2(hp0, hp1);                                 \
        *(uint2*)&Hl[adr] = make_uint2(lp0, lp1);                                 \
    } }

#define MFMA_PHASE {                                                              \
    short8 af[8], bh[4], bl[4];                                                   \
    _Pragma("unroll") for (int mi = 0; mi < 8; ++mi) {                            \
        int r = wr + mi * 16 + fr;                                                \
        af[mi] = *(const short8*)&Hh[r * 32 + ((fg ^ (r & 3)) * 8)];              \
    }                                                                             \
    _Pragma("unroll") for (int nj = 0; nj < 4; ++nj) {                            \
        int r = wc + nj * 16 + fr;                                                \
        int adr = r * 32 + ((fg ^ (r & 3)) * 8);                                  \
        bh[nj] = *(const short8*)&Hh[adr];                                        \
        bl[nj] = *(const short8*)&Hl[adr];                                        \
    }                                                                             \
    _Pragma("unroll") for (int mi = 0; mi < 8; ++mi)                              \
        _Pragma("unroll") for (int nj = 0; nj < 4; ++nj) {                        \
            acc[mi][nj] = __builtin_amdgcn_mfma_f32_16x16x32_bf16(af[mi], bh[nj], acc[mi][nj], 0, 0, 0); \
            acc[mi][nj] = __builtin_amdgcn_mfma_f32_16x16x32_bf16(af[mi], bl[nj], acc[mi][nj], 0, 0, 0); \
        } }

    // prologue
    ISSUE(0, 0)
#pragma unroll 2
    for (int kb = 0; kb < 16; ++kb) {
        if (kb < 15) {
            ISSUE(kb + 1, (kb + 1) & 1)
            asm volatile("s_waitcnt vmcnt(4)" ::: "memory");   // kb's DMA landed (per-wave)
        } else {
            asm volatile("s_waitcnt vmcnt(0)" ::: "memory");
        }
        __builtin_amdgcn_sched_barrier(0);
        __builtin_amdgcn_s_barrier();        // all waves: DMA(kb) visible; prev MFMA reads done
        CONVERT(kb & 1)
        asm volatile("s_waitcnt lgkmcnt(0)" ::: "memory");     // Hh/Hl writes complete
        __builtin_amdgcn_sched_barrier(0);
        __builtin_amdgcn_s_barrier();        // tile ready for all waves
        MFMA_PHASE
    }

    // s/sq partial reduction across the 8 granule lanes of each row
#pragma unroll
    for (int j = 0; j < 4; ++j) {
#pragma unroll
        for (int off = 1; off < 8; off <<= 1) {
            sl[j] += __shfl_xor(sl[j], off);
            sql[j] += __shfl_xor(sql[j], off);
        }
    }
    if (gs == 0) {
#pragma unroll
        for (int j = 0; j < 4; ++j) {
            int row = w * 32 + j * 8 + rl;
            sP[(size_t)z * CH + row] = sl[j];
            sqP[(size_t)z * CH + row] = sql[j];
        }
    }

    float* Cp = cosP + (size_t)z * CH * CH;
#pragma unroll
    for (int mi = 0; mi < 8; ++mi)
#pragma unroll
        for (int nj = 0; nj < 4; ++nj) {
#pragma unroll
            for (int reg = 0; reg < 4; ++reg) {
                int r = wr + mi * 16 + fg * 4 + reg;
                int c = wc + nj * 16 + fr;
                Cp[(size_t)r * CH + c] = acc[mi][nj][reg];
            }
        }
#undef ISSUE
#undef CONVERT
#undef MFMA_PHASE
}

// ---- K2: finalize per-(b,c) stats from the 8 q-partials ----
__global__ __launch_bounds__(256) void finalize_kernel(const float* __restrict__ sP,
                                                       const float* __restrict__ sqP,
                                                       float* __restrict__ s,
                                                       float* __restrict__ sq,
                                                       float* __restrict__ invn) {
    int b = blockIdx.x, c = threadIdx.x;
    float S = 0.f, Q = 0.f;
#pragma unroll
    for (int q = 0; q < 8; ++q) {
        S += sP[(size_t)(b * 8 + q) * CH + c];
        Q += sqP[(size_t)(b * 8 + q) * CH + c];
    }
    s[b * CH + c] = S;
    sq[b * CH + c] = Q;
    invn[b * CH + c] = 1.0f / fmaxf(sqrtf(Q), 1e-12f);
}

// ---- K3: weighted sum of partials -> R[256][256] (invn applied per batch) ----
__global__ __launch_bounds__(1024) void reduceP(const float* __restrict__ cosP,
                                                const float* __restrict__ invn,
                                                float* __restrict__ R) {
    int r = blockIdx.x;
    int t = threadIdx.x;
    int d = t & 255, pg = t >> 8;          // 4 groups of 8 batches
    const float* base = cosP + (size_t)r * CH + d;
    float acc = 0.f;
    for (int b = pg * 8; b < pg * 8 + 8; ++b) {
        float part = 0.f;
#pragma unroll
        for (int q = 0; q < 8; ++q)
            part += base[(size_t)(b * 8 + q) * (CH * CH)];
        acc += part * invn[b * CH + d] * invn[b * CH + r];
    }
    __shared__ float red[1024];
    red[t] = acc;
    __syncthreads();
    if (t < 256)
        R[(size_t)r * CH + t] = red[t] + red[t + 256] + red[t + 512] + red[t + 768];
}

// -------- K4: symmetrize (R + R^T) + top-8 smallest |cos| per column --------
__global__ __launch_bounds__(256) void symtopk(const float* __restrict__ R,
                                               int* __restrict__ idx) {
    int c = blockIdx.x;
    int d = threadIdx.x;
    float v = fabsf((R[(size_t)c * CH + d] + R[(size_t)d * CH + c]) * (0.5f / BATCH));

    __shared__ unsigned long long keys[CH];
    __shared__ unsigned long long wmin[4];
    __shared__ unsigned long long bmin;

    keys[d] = ((unsigned long long)__float_as_uint(v) << 32) | (unsigned)d;
    __syncthreads();

    for (int i = 0; i < KSEL; ++i) {
        unsigned long long k = keys[d];
        for (int off = 32; off; off >>= 1) {
            unsigned long long o = __shfl_down(k, off);
            k = (o < k) ? o : k;
        }
        if ((d & 63) == 0) wmin[d >> 6] = k;
        __syncthreads();
        if (d == 0) {
            unsigned long long m = wmin[0];
            if (wmin[1] < m) m = wmin[1];
            if (wmin[2] < m) m = wmin[2];
            if (wmin[3] < m) m = wmin[3];
            bmin = m;
            idx[c * KSEL + i] = (int)(m & 0xffffffffu);
        }
        __syncthreads();
        int sel = (int)(bmin & 0xffffffffu);
        if (d == sel) keys[d] = 0xffffffffffffffffULL;
        __syncthreads();
    }
}

// ---------------- K5: gathered group statistics ----------------
__global__ __launch_bounds__(256) void groupstat_kernel(const float* __restrict__ s,
                                                        const float* __restrict__ sq,
                                                        const int* __restrict__ idx,
                                                        float* __restrict__ mean,
                                                        float* __restrict__ inv) {
    int b = blockIdx.x, c = threadIdx.x;
    float gs = s[b * CH + c], gq = sq[b * CH + c];
#pragma unroll
    for (int i = 1; i < KSEL; ++i) {
        int d = idx[c * KSEL + i];
        gs += s[b * CH + d];
        gq += sq[b * CH + d];
    }
    const float Ninv = 1.0f / (float)(KSEL * HW);
    float m = gs * Ninv;
    float var = gq * Ninv - m * m;
    mean[b * CH + c] = m;
    inv[b * CH + c]  = rsqrtf(var + EPSV);
}

// ---------------- K6: normalize ----------------
__global__ __launch_bounds__(256) void norm_kernel(const float* __restrict__ x,
                                                   const float* __restrict__ mean,
                                                   const float* __restrict__ inv,
                                                   const float* __restrict__ gamma,
                                                   const float* __restrict__ beta,
                                                   float* __restrict__ out) {
    int i = blockIdx.x * 256 + threadIdx.x;
    int bc = i >> 10;
    int c  = bc & (CH - 1);
    float m = mean[bc], v = inv[bc];
    float g  = gamma[c] * v;
    float bt = beta[c] - m * g;
    float4 xv = ((const float4*)x)[i];
    float4 o;
    o.x = xv.x * g + bt;
    o.y = xv.y * g + bt;
    o.z = xv.z * g + bt;
    o.w = xv.w * g + bt;
    ((float4*)out)[i] = o;
}

extern "C" void kernel_launch(void* const* d_in, const int* in_sizes, int n_in,
                              void* d_out, int out_size, void* d_ws, size_t ws_size,
                              hipStream_t stream) {
    const float* x     = (const float*)d_in[0];
    const float* gamma = (const float*)d_in[1];
    const float* beta  = (const float*)d_in[2];
    float* out = (float*)d_out;

    // Gram partials (256 x 256KB = 64 MB) live in d_out; norm overwrites at end.
    float* cosP = (float*)d_out;

    float* ws   = (float*)d_ws;
    float* sP   = ws;                         // 256*256 partial s
    float* sqP  = sP + 256 * CH;              // 256*256 partial sq
    float* s    = sqP + 256 * CH;
    float* sq   = s + BATCH * CH;
    float* invn = sq + BATCH * CH;
    float* mean = invn + BATCH * CH;
    float* inv  = mean + BATCH * CH;
    float* R    = inv + BATCH * CH;           // 256*256
    int*   idx  = (int*)(R + CH * CH);        // 256*8

    gram256<<<256, 512, 0, stream>>>(x, cosP, sP, sqP);
    finalize_kernel<<<BATCH, 256, 0, stream>>>(sP, sqP, s, sq, invn);
    reduceP<<<CH, 1024, 0, stream>>>(cosP, invn, R);
    symtopk<<<CH, 256, 0, stream>>>(R, idx);
    groupstat_kernel<<<BATCH, 256, 0, stream>>>(s, sq, idx, mean, inv);
    norm_kernel<<<(BATCH * CH * HW / 4) / 256, 256, 0, stream>>>(x, mean, inv, gamma, beta, out);
}